// Round 1
// baseline (643.769 us; speedup 1.0000x reference)
//
#include <hip/hip_runtime.h>
#include <math.h>

typedef _Float16 half_t;
typedef __attribute__((ext_vector_type(8))) _Float16 f16x8;
typedef __attribute__((ext_vector_type(4))) _Float16 f16x4;
typedef __attribute__((ext_vector_type(4))) float f32x4;

#define MFMA16(a, b, c) __builtin_amdgcn_mfma_f32_16x16x32_f16((a), (b), (c), 0, 0, 0)

constexpr int Bc = 4, NQ = 2048, NKC = 2048, CC = 1024, NHD = 16, HDIM = 64;

__device__ __forceinline__ void async_copy16(half_t* lds, const half_t* g) {
  __builtin_amdgcn_global_load_lds(
      (const __attribute__((address_space(1))) unsigned*)g,
      (__attribute__((address_space(3))) unsigned*)lds, 16, 0, 0);
}

// ---------------------------------------------------------------------------
// fp32 -> fp16 converts (8 elems/thread)
// ---------------------------------------------------------------------------
__global__ __launch_bounds__(256) void cvt16(const float* __restrict__ src,
                                             half_t* __restrict__ dst) {
  const int i = blockIdx.x * 256 + threadIdx.x;
  const f32x4 a = ((const f32x4*)src)[2 * i];
  const f32x4 b = ((const f32x4*)src)[2 * i + 1];
  f16x8 h;
#pragma unroll
  for (int j = 0; j < 4; ++j) { h[j] = (half_t)a[j]; h[4 + j] = (half_t)b[j]; }
  ((f16x8*)dst)[i] = h;
}

__global__ __launch_bounds__(256) void cvtW(const float* __restrict__ s0,
                                            const float* __restrict__ s1,
                                            const float* __restrict__ s2,
                                            const float* __restrict__ s3,
                                            half_t* __restrict__ dst) {
  const int y = blockIdx.y;
  const float* src = (y == 0) ? s0 : (y == 1) ? s1 : (y == 2) ? s2 : s3;
  const int i = blockIdx.x * 256 + threadIdx.x;
  const f32x4 a = ((const f32x4*)src)[2 * i];
  const f32x4 b = ((const f32x4*)src)[2 * i + 1];
  f16x8 h;
#pragma unroll
  for (int j = 0; j < 4; ++j) { h[j] = (half_t)a[j]; h[4 + j] = (half_t)b[j]; }
  ((f16x8*)(dst + (size_t)y * CC * CC))[i] = h;
}

// ---------------------------------------------------------------------------
// GEMM (m97 structure): out[m][n] = sum_k X[m][k]*W[n][k], fp16 in, MFMA.
// 128x128 tile, BK=32, unpadded LDS, global_load_lds width 16.
// ---------------------------------------------------------------------------
template <bool FINAL>
__global__ __launch_bounds__(256) void gemm_lds(const half_t* __restrict__ X,
                                                const half_t* __restrict__ W,
                                                half_t* __restrict__ out16,
                                                float* __restrict__ outf,
                                                const float* __restrict__ bias) {
  __shared__ half_t As[128 * 32];
  __shared__ half_t Bs[128 * 32];
  const int tid  = threadIdx.x;
  const int wave = tid >> 6, lane = tid & 63;
  const int quad = lane >> 4, l16 = lane & 15;
  const int m0 = blockIdx.y * 128, n0 = blockIdx.x * 128;
  const int mw = (wave >> 1) * 64, nw = (wave & 1) * 64;

  // staging: instr i in {0,1} covers rows wave*32+i*16 .. +16, lane: row+=l/4, k=(l&3)*8
  const int srow = lane >> 2, skoff = (lane & 3) * 8;
  const half_t* xa = X + (size_t)(m0 + wave * 32 + srow) * CC + skoff;
  const half_t* xb = W + (size_t)(n0 + wave * 32 + srow) * CC + skoff;
  half_t* lA0 = &As[(wave * 2 + 0) * 512];
  half_t* lA1 = &As[(wave * 2 + 1) * 512];
  half_t* lB0 = &Bs[(wave * 2 + 0) * 512];
  half_t* lB1 = &Bs[(wave * 2 + 1) * 512];

  f32x4 acc[4][4] = {};

  for (int k0 = 0; k0 < CC; k0 += 32) {
    __syncthreads();
    async_copy16(lA0, xa + k0);
    async_copy16(lA1, xa + 16 * CC + k0);
    async_copy16(lB0, xb + k0);
    async_copy16(lB1, xb + 16 * CC + k0);
    __syncthreads();

    f16x8 af[4], bf[4];
#pragma unroll
    for (int mi = 0; mi < 4; ++mi) af[mi] = *(const f16x8*)&As[(mw + mi * 16 + l16) * 32 + quad * 8];
#pragma unroll
    for (int ni = 0; ni < 4; ++ni) bf[ni] = *(const f16x8*)&Bs[(nw + ni * 16 + l16) * 32 + quad * 8];
#pragma unroll
    for (int mi = 0; mi < 4; ++mi)
#pragma unroll
      for (int ni = 0; ni < 4; ++ni) acc[mi][ni] = MFMA16(af[mi], bf[ni], acc[mi][ni]);
  }

#pragma unroll
  for (int mi = 0; mi < 4; ++mi)
#pragma unroll
    for (int ni = 0; ni < 4; ++ni)
#pragma unroll
      for (int r = 0; r < 4; ++r) {
        const size_t row = (size_t)(m0 + mw + mi * 16 + quad * 4 + r);
        const size_t col = (size_t)(n0 + nw + ni * 16 + l16);
        if constexpr (FINAL) outf[row * CC + col] = acc[mi][ni][r] + bias[col];
        else                 out16[row * CC + col] = (half_t)acc[mi][ni][r];
      }
}

// ---------------------------------------------------------------------------
// RoPE2D in fp16, in place (exact numpy-fp16 elementwise emulation).
// ---------------------------------------------------------------------------
__global__ __launch_bounds__(256) void rope_kernel(half_t* __restrict__ t,
                                                   const int* __restrict__ pos) {
#pragma clang fp contract(off)
  const int gid = blockIdx.x * 256 + threadIdx.x;
  const int i       = gid & 15;
  const int halfsel = (gid >> 4) & 1;
  const int h       = (gid >> 5) & 15;
  const int n       = (gid >> 9) & 2047;
  const int b       = gid >> 20;

  const int p = pos[((b * NQ + n) << 1) + halfsel];
  const float inv = __builtin_amdgcn_exp2f((float)i * -0.41524100904865773f);
  const float ang = (float)p * inv;
  const half_t hc = (half_t)cosf(ang);
  const half_t hs = (half_t)sinf(ang);

  const size_t base = (size_t)(b * NQ + n) * CC + h * HDIM + halfsel * 32;
  const half_t t1 = t[base + i];
  const half_t t2 = t[base + 16 + i];
  const half_t p1 = t1 * hc;
  const half_t p2 = t2 * hs;
  const half_t p3 = t2 * hc;
  const half_t p4 = t1 * hs;
  t[base + i]      = p1 - p2;
  t[base + 16 + i] = p3 + p4;
}

// ---------------------------------------------------------------------------
// Flash attention, swapped-operand form.
//   S^T = mfma(K-frag, Q-frag)  -> lane holds P[q=l16][keys kb*16+quad*4+r]
//   P packs in-lane into key-pair dwords -> 8 KB swizzled per-wave Pb
//   O^T = mfma(V^T-frag, P-frag) -> per-lane contiguous d, vector stores
// All LDS layouts are fragment-ordered and XOR-swizzled: every ds op is
// <=2-way (free). LDS total 24 KB -> 6 blocks/CU capacity.
// ---------------------------------------------------------------------------
__global__ __launch_bounds__(256, 4) void attn_kernel(const half_t* __restrict__ q16,
                                                      const half_t* __restrict__ k16,
                                                      const half_t* __restrict__ v16,
                                                      half_t* __restrict__ x16) {
  // K fragments: [nb][kc][quad*16+l16][8 halfs]   (8 KB)
  __shared__ __align__(16) half_t Kf[4 * 2 * 64 * 8];
  // V^T fragments: [kc][nd][slot'][8 halfs], slot' = quad*16 + (l16 ^ quad ^ (kc<<2))  (8 KB)
  __shared__ __align__(16) unsigned Vfd[2 * 4 * 64 * 4];
  // P key-pair dwords: [wave][q=l16][m ^ ((l16&7)<<2)], m = key/2   (8 KB)
  __shared__ __align__(16) unsigned Pb[4][16][32];

  const int tid  = threadIdx.x;
  const int wave = tid >> 6, lane = tid & 63;
  const int quad = lane >> 4, l16 = lane & 15;
  const int lx   = lane ^ quad;  // V-read slot base (quad XORed into low bits)
  const int qblk = blockIdx.x, h = blockIdx.y, b = blockIdx.z;
  const f32x4 zero = {0.f, 0.f, 0.f, 0.f};

  // Q fragments: rows wave*32 + mi*16 + l16, k = kc*32 + quad*8 (B-operand role)
  f16x8 qa[2][2];
  {
    const half_t* qbase =
        q16 + (size_t)(b * NQ + qblk * 128 + wave * 32 + l16) * CC + h * HDIM + quad * 8;
#pragma unroll
    for (int mi = 0; mi < 2; ++mi)
#pragma unroll
      for (int kc = 0; kc < 2; ++kc)
        qa[mi][kc] = *(const f16x8*)(qbase + (size_t)mi * 16 * CC + kc * 32);
  }

  f32x4 o[2][4] = {};     // O^T fragments: [mi][nd], rows d = nd*16+quad*4+r, col q = l16
  float lp[2] = {};       // per-lane partial row sums (q = mi*16 + l16)

  // K staging: thread covers key=skey, d = sd0..sd0+15
  const int skey = tid >> 2, sd0 = (tid & 3) * 16;
  const half_t* kptr = k16 + (size_t)(b * NKC + skey) * CC + h * HDIM + sd0;
  int kdst[2];
#pragma unroll
  for (int c = 0; c < 2; ++c) {
    const int d = sd0 + 8 * c;
    const int kc = d >> 5, qd = (d & 31) >> 3;
    kdst[c] = ((((skey >> 4) * 2 + kc) * 64) + qd * 16 + (skey & 15)) * 8;
  }

  // V staging: thread covers keys {2vp, 2vp+1}, d = vd0..vd0+7
  const int vp = tid & 31, vd0 = (tid >> 5) * 8;
  const half_t* vptr = v16 + (size_t)(b * NKC + 2 * vp) * CC + h * HDIM + vd0;
  const int vkc = vp >> 4, vqd = (vp & 15) >> 2, vnd = vd0 >> 4;
  const int vl16b = vd0 & 15;                       // 0 or 8
  const int vswz  = vqd ^ (vkc << 2);
  const int vbase = ((vkc * 4 + vnd) * 64 + vqd * 16) * 4 + (vp & 3);

  f16x8 kr0, kr1, vr0, vr1;
  kr0 = *(const f16x8*)kptr;
  kr1 = *(const f16x8*)(kptr + 8);
  vr0 = *(const f16x8*)vptr;
  vr1 = *(const f16x8*)(vptr + CC);

  for (int kt = 0; kt < NKC; kt += 64) {
    __syncthreads();
    *(f16x8*)&Kf[kdst[0]] = kr0;
    *(f16x8*)&Kf[kdst[1]] = kr1;
#pragma unroll
    for (int i = 0; i < 8; ++i) {
      union { half_t h2[2]; unsigned u; } pk;
      pk.h2[0] = vr0[i]; pk.h2[1] = vr1[i];
      Vfd[vbase + (((vl16b + i) ^ vswz) << 2)] = pk.u;
    }
    __syncthreads();

    if (kt + 64 < NKC) {  // prefetch next tile into registers (overlaps compute)
      const half_t* kn = kptr + (size_t)(kt + 64) * CC;
      const half_t* vn = vptr + (size_t)(kt + 64) * CC;
      kr0 = *(const f16x8*)kn;
      kr1 = *(const f16x8*)(kn + 8);
      vr0 = *(const f16x8*)vn;
      vr1 = *(const f16x8*)(vn + CC);
    }

    // mi-serial over the shared Pb buffer
#pragma unroll
    for (int mi = 0; mi < 2; ++mi) {
      // S^T = K . Q^T : lane holds S^T[key = kb*16+quad*4+r][q = mi*16+l16]
      f32x4 st[4];
#pragma unroll
      for (int kb = 0; kb < 4; ++kb) {
        const f16x8 ka0 = *(const f16x8*)&Kf[((kb * 2 + 0) * 64 + lane) * 8];
        const f16x8 ka1 = *(const f16x8*)&Kf[((kb * 2 + 1) * 64 + lane) * 8];
        const f32x4 t0 = MFMA16(ka0, qa[mi][0], zero);
        st[kb] = MFMA16(ka1, qa[mi][1], t0);
      }

      // p = exp2(s * 0.125*log2 e); pack key-pairs in-lane; write swizzled Pb
#pragma unroll
      for (int kb = 0; kb < 4; ++kb) {
        f16x4 w;
#pragma unroll
        for (int r = 0; r < 4; ++r) {
          const float p = __builtin_amdgcn_exp2f(st[kb][r] * 0.18033688011112042f);
          lp[mi] += p;
          w[r] = (half_t)p;
        }
        const int m0 = kb * 8 + quad * 2;  // key-pair index (even)
        *(f16x4*)&Pb[wave][l16][m0 ^ ((l16 & 7) << 2)] = w;
      }

      // O^T += V^T . P^T
#pragma unroll
      for (int kc = 0; kc < 2; ++kc) {
        const f16x8 pa = *(const f16x8*)&Pb[wave][l16][(kc * 16 + quad * 4) ^ ((l16 & 7) << 2)];
#pragma unroll
        for (int nd = 0; nd < 4; ++nd) {
          const f16x8 vb = *(const f16x8*)&Vfd[(((kc * 4 + nd) * 64) + (lx ^ (kc << 2))) * 4];
          o[mi][nd] = MFMA16(vb, pa, o[mi][nd]);
        }
      }
    }
  }

  // epilogue: row sum over quads, normalize, contiguous 8B stores
#pragma unroll
  for (int mi = 0; mi < 2; ++mi) {
    float rs = lp[mi];
    rs += __shfl_xor(rs, 16);
    rs += __shfl_xor(rs, 32);
    const float inv = 1.f / rs;
    const size_t row =
        (size_t)(b * NQ + qblk * 128 + wave * 32 + mi * 16 + l16) * CC + h * HDIM;
#pragma unroll
    for (int nd = 0; nd < 4; ++nd) {
      f16x4 w;
#pragma unroll
      for (int r = 0; r < 4; ++r) w[r] = (half_t)(o[mi][nd][r] * inv);
      *(f16x4*)&x16[row + nd * 16 + quad * 4] = w;
    }
  }
}

// ---------------------------------------------------------------------------
extern "C" void kernel_launch(void* const* d_in, const int* in_sizes, int n_in,
                              void* d_out, int out_size, void* d_ws, size_t ws_size,
                              hipStream_t stream) {
  const float* query = (const float*)d_in[0];
  const float* key   = (const float*)d_in[1];
  const float* value = (const float*)d_in[2];
  const int*   qpos  = (const int*)d_in[3];
  const int*   kpos  = (const int*)d_in[4];
  const float* Wq = (const float*)d_in[5];
  const float* Wk = (const float*)d_in[6];
  const float* Wv = (const float*)d_in[7];
  const float* Wo = (const float*)d_in[8];
  const float* bo = (const float*)d_in[9];
  float* out = (float*)d_out;

  const size_t NT = (size_t)Bc * NQ * CC;  // 8.4M halfs per activation tensor
  half_t* q16 = (half_t*)d_ws;
  half_t* k16 = q16 + NT;
  half_t* v16 = k16 + NT;
  half_t* A0  = v16 + NT;        // fp16 staging for GEMM X input; later x16
  half_t* W16 = A0 + NT;         // 4 weights, fp16, 1M each
  half_t* x16 = A0;

  const int nbA = (int)(NT / 8 / 256);      // 4096 blocks for activation cvt
  const int nbW = (CC * CC) / 8 / 256;      // 512 blocks per weight

  // weights -> fp16 (one batched launch)
  cvtW<<<dim3(nbW, 4), 256, 0, stream>>>(Wq, Wk, Wv, Wo, W16);

  const dim3 gg(CC / 128, Bc * NQ / 128);  // (8, 64)
  // Q/K/V projections (A0 reused serially; stream order serializes)
  cvt16<<<nbA, 256, 0, stream>>>(query, A0);
  gemm_lds<false><<<gg, 256, 0, stream>>>(A0, W16 + 0 * (size_t)CC * CC, q16, nullptr, nullptr);
  cvt16<<<nbA, 256, 0, stream>>>(key, A0);
  gemm_lds<false><<<gg, 256, 0, stream>>>(A0, W16 + 1 * (size_t)CC * CC, k16, nullptr, nullptr);
  cvt16<<<nbA, 256, 0, stream>>>(value, A0);
  gemm_lds<false><<<gg, 256, 0, stream>>>(A0, W16 + 2 * (size_t)CC * CC, v16, nullptr, nullptr);

  rope_kernel<<<(Bc * NQ * NHD * 32) / 256, 256, 0, stream>>>(q16, qpos);
  rope_kernel<<<(Bc * NQ * NHD * 32) / 256, 256, 0, stream>>>(k16, kpos);

  attn_kernel<<<dim3(NQ / 128, NHD, Bc), 256, 0, stream>>>(q16, k16, v16, x16);

  gemm_lds<true><<<gg, 256, 0, stream>>>(x16, W16 + 3 * (size_t)CC * CC, nullptr, out, bo);
}

// Round 2
// 463.440 us; speedup vs baseline: 1.3891x; 1.3891x over previous
//
#include <hip/hip_runtime.h>
#include <math.h>

typedef _Float16 half_t;
typedef __attribute__((ext_vector_type(8))) _Float16 f16x8;
typedef __attribute__((ext_vector_type(4))) _Float16 f16x4;
typedef __attribute__((ext_vector_type(4))) float f32x4;

#define MFMA16(a, b, c) __builtin_amdgcn_mfma_f32_16x16x32_f16((a), (b), (c), 0, 0, 0)

constexpr int Bc = 4, NQ = 2048, NKC = 2048, CC = 1024, NHD = 16, HDIM = 64;

__device__ __forceinline__ void async_copy16(half_t* lds, const half_t* g) {
  __builtin_amdgcn_global_load_lds(
      (const __attribute__((address_space(1))) unsigned*)g,
      (__attribute__((address_space(3))) unsigned*)lds, 16, 0, 0);
}

// ---------------------------------------------------------------------------
// fp32 -> fp16 converts (8 elems/thread)
// ---------------------------------------------------------------------------
__global__ __launch_bounds__(256) void cvt16(const float* __restrict__ src,
                                             half_t* __restrict__ dst) {
  const int i = blockIdx.x * 256 + threadIdx.x;
  const f32x4 a = ((const f32x4*)src)[2 * i];
  const f32x4 b = ((const f32x4*)src)[2 * i + 1];
  f16x8 h;
#pragma unroll
  for (int j = 0; j < 4; ++j) { h[j] = (half_t)a[j]; h[4 + j] = (half_t)b[j]; }
  ((f16x8*)dst)[i] = h;
}

__global__ __launch_bounds__(256) void cvtW(const float* __restrict__ s0,
                                            const float* __restrict__ s1,
                                            const float* __restrict__ s2,
                                            const float* __restrict__ s3,
                                            half_t* __restrict__ dst) {
  const int y = blockIdx.y;
  const float* src = (y == 0) ? s0 : (y == 1) ? s1 : (y == 2) ? s2 : s3;
  const int i = blockIdx.x * 256 + threadIdx.x;
  const f32x4 a = ((const f32x4*)src)[2 * i];
  const f32x4 b = ((const f32x4*)src)[2 * i + 1];
  f16x8 h;
#pragma unroll
  for (int j = 0; j < 4; ++j) { h[j] = (half_t)a[j]; h[4 + j] = (half_t)b[j]; }
  ((f16x8*)(dst + (size_t)y * CC * CC))[i] = h;
}

// ---------------------------------------------------------------------------
// GEMM (m97 structure): out[m][n] = sum_k X[m][k]*W[n][k], fp16 in, MFMA.
// 128x128 tile, BK=32, unpadded LDS, global_load_lds width 16.
// ---------------------------------------------------------------------------
template <bool FINAL>
__global__ __launch_bounds__(256) void gemm_lds(const half_t* __restrict__ X,
                                                const half_t* __restrict__ W,
                                                half_t* __restrict__ out16,
                                                float* __restrict__ outf,
                                                const float* __restrict__ bias) {
  __shared__ half_t As[128 * 32];
  __shared__ half_t Bs[128 * 32];
  const int tid  = threadIdx.x;
  const int wave = tid >> 6, lane = tid & 63;
  const int quad = lane >> 4, l16 = lane & 15;
  const int m0 = blockIdx.y * 128, n0 = blockIdx.x * 128;
  const int mw = (wave >> 1) * 64, nw = (wave & 1) * 64;

  // staging: instr i in {0,1} covers rows wave*32+i*16 .. +16, lane: row+=l/4, k=(l&3)*8
  const int srow = lane >> 2, skoff = (lane & 3) * 8;
  const half_t* xa = X + (size_t)(m0 + wave * 32 + srow) * CC + skoff;
  const half_t* xb = W + (size_t)(n0 + wave * 32 + srow) * CC + skoff;
  half_t* lA0 = &As[(wave * 2 + 0) * 512];
  half_t* lA1 = &As[(wave * 2 + 1) * 512];
  half_t* lB0 = &Bs[(wave * 2 + 0) * 512];
  half_t* lB1 = &Bs[(wave * 2 + 1) * 512];

  f32x4 acc[4][4] = {};

  for (int k0 = 0; k0 < CC; k0 += 32) {
    __syncthreads();
    async_copy16(lA0, xa + k0);
    async_copy16(lA1, xa + 16 * CC + k0);
    async_copy16(lB0, xb + k0);
    async_copy16(lB1, xb + 16 * CC + k0);
    __syncthreads();

    f16x8 af[4], bf[4];
#pragma unroll
    for (int mi = 0; mi < 4; ++mi) af[mi] = *(const f16x8*)&As[(mw + mi * 16 + l16) * 32 + quad * 8];
#pragma unroll
    for (int ni = 0; ni < 4; ++ni) bf[ni] = *(const f16x8*)&Bs[(nw + ni * 16 + l16) * 32 + quad * 8];
#pragma unroll
    for (int mi = 0; mi < 4; ++mi)
#pragma unroll
      for (int ni = 0; ni < 4; ++ni) acc[mi][ni] = MFMA16(af[mi], bf[ni], acc[mi][ni]);
  }

#pragma unroll
  for (int mi = 0; mi < 4; ++mi)
#pragma unroll
    for (int ni = 0; ni < 4; ++ni)
#pragma unroll
      for (int r = 0; r < 4; ++r) {
        const size_t row = (size_t)(m0 + mw + mi * 16 + quad * 4 + r);
        const size_t col = (size_t)(n0 + nw + ni * 16 + l16);
        if constexpr (FINAL) outf[row * CC + col] = acc[mi][ni][r] + bias[col];
        else                 out16[row * CC + col] = (half_t)acc[mi][ni][r];
      }
}

// ---------------------------------------------------------------------------
// RoPE2D in fp16, in place (exact numpy-fp16 elementwise emulation).
// ---------------------------------------------------------------------------
__global__ __launch_bounds__(256) void rope_kernel(half_t* __restrict__ t,
                                                   const int* __restrict__ pos) {
#pragma clang fp contract(off)
  const int gid = blockIdx.x * 256 + threadIdx.x;
  const int i       = gid & 15;
  const int halfsel = (gid >> 4) & 1;
  const int h       = (gid >> 5) & 15;
  const int n       = (gid >> 9) & 2047;
  const int b       = gid >> 20;

  const int p = pos[((b * NQ + n) << 1) + halfsel];
  const float inv = __builtin_amdgcn_exp2f((float)i * -0.41524100904865773f);
  const float ang = (float)p * inv;
  const half_t hc = (half_t)cosf(ang);
  const half_t hs = (half_t)sinf(ang);

  const size_t base = (size_t)(b * NQ + n) * CC + h * HDIM + halfsel * 32;
  const half_t t1 = t[base + i];
  const half_t t2 = t[base + 16 + i];
  const half_t p1 = t1 * hc;
  const half_t p2 = t2 * hs;
  const half_t p3 = t2 * hc;
  const half_t p4 = t1 * hs;
  t[base + i]      = p1 - p2;
  t[base + 16 + i] = p3 + p4;
}

// ---------------------------------------------------------------------------
// Flash attention, swapped-operand form, spill-free restructure.
//   K: double-buffered global_load_lds with pre-swizzled per-lane source
//      (fragment-ordered LDS layout, wave-uniform dest base + lane*16).
//   V: reg-staged (transpose pack), single LDS buffer, dword-swizzled.
//   S^T = mfma(K-frag, Q-frag); per-kb exp+pack (4-VGPR live range);
//   P via 8 KB swizzled per-wave Pb; O^T = mfma(V^T-frag, P-frag).
// LDS = 16 + 8 + 8 = 32 KB -> 5 blocks/CU capacity.
// ---------------------------------------------------------------------------
__global__ __launch_bounds__(256, 3) void attn_kernel(const half_t* __restrict__ q16,
                                                      const half_t* __restrict__ k16,
                                                      const half_t* __restrict__ v16,
                                                      half_t* __restrict__ x16) {
  // K fragments, double-buffered: [buf][kb][kc][slot=quad*16+l16][8 halfs] (16 KB)
  __shared__ __align__(16) half_t Kf[2 * 4096];
  // V^T fragments: [kc][nd][slot'][8 halfs], slot' = quad*16 + (l16 ^ quad ^ (kc<<2)) (8 KB)
  __shared__ __align__(16) unsigned Vfd[2 * 4 * 64 * 4];
  // P key-pair dwords: [wave][q=l16][m ^ ((l16&7)<<2)], m = key/2 (8 KB)
  __shared__ __align__(16) unsigned Pb[4][16][32];

  const int tid  = threadIdx.x;
  const int wave = tid >> 6, lane = tid & 63;
  const int quad = lane >> 4, l16 = lane & 15;
  const int lx   = lane ^ quad;  // V-read slot base (quad XORed into low bits)
  const int qblk = blockIdx.x, h = blockIdx.y, b = blockIdx.z;
  const f32x4 zero = {0.f, 0.f, 0.f, 0.f};

  // Q fragments (B-operand role): rows wave*32 + mi*16 + l16, k = kc*32 + quad*8
  f16x8 qa[2][2];
  {
    const half_t* qbase =
        q16 + (size_t)(b * NQ + qblk * 128 + wave * 32 + l16) * CC + h * HDIM + quad * 8;
#pragma unroll
    for (int mi = 0; mi < 2; ++mi)
#pragma unroll
      for (int kc = 0; kc < 2; ++kc)
        qa[mi][kc] = *(const f16x8*)(qbase + (size_t)mi * 16 * CC + kc * 32);
  }

  f32x4 o[2][4] = {};  // O^T fragments: [mi][nd], rows d = nd*16+quad*4+r, col q = l16
  float lp[2] = {};    // per-lane partial row sums (q = mi*16 + l16)

  // K gll: wave w stages kb=w. Per-lane global source so linear LDS dest
  // (base + lane*16) lands in fragment order: key = w*16 + l16, d = quad*8 + kc*32.
  const half_t* kga = k16 + (size_t)(b * NKC + wave * 16 + l16) * CC + h * HDIM + quad * 8;

  // V staging: thread covers keys {2vp, 2vp+1}, d = vd0..vd0+7
  const int vp = tid & 31, vd0 = (tid >> 5) * 8;
  const half_t* vptr = v16 + (size_t)(b * NKC + 2 * vp) * CC + h * HDIM + vd0;
  const int vkc = vp >> 4, vqd = (vp & 15) >> 2, vnd = vd0 >> 4;
  const int vl16b = vd0 & 15;  // 0 or 8
  const int vswz  = vqd ^ (vkc << 2);
  const int vbase = ((vkc * 4 + vnd) * 64 + vqd * 16) * 4 + (vp & 3);

  // prologue: tile 0 in flight
  async_copy16(&Kf[(wave * 2 + 0) * 512], kga);
  async_copy16(&Kf[(wave * 2 + 1) * 512], kga + 32);
  f16x8 vr0 = *(const f16x8*)vptr;
  f16x8 vr1 = *(const f16x8*)(vptr + CC);

  int cur = 0;
  for (int kt = 0; kt < NKC; kt += 64) {
    // V transpose-pack into Vfd (this tile); prior-iter barrier guarantees no readers
#pragma unroll
    for (int i = 0; i < 8; ++i) {
      union { half_t h2[2]; unsigned u; } pk;
      pk.h2[0] = vr0[i]; pk.h2[1] = vr1[i];
      Vfd[vbase + (((vl16b + i) ^ vswz) << 2)] = pk.u;
    }
    __syncthreads();  // vmcnt(0) drains gll -> Kf[cur] ready; Vfd visible

    if (kt + 64 < NKC) {  // issue next K tile (other buffer) + next V reg loads
      const half_t* kn = kga + (size_t)(kt + 64) * CC;
      async_copy16(&Kf[(cur ^ 1) * 4096 + (wave * 2 + 0) * 512], kn);
      async_copy16(&Kf[(cur ^ 1) * 4096 + (wave * 2 + 1) * 512], kn + 32);
      const half_t* vn = vptr + (size_t)(kt + 64) * CC;
      vr0 = *(const f16x8*)vn;
      vr1 = *(const f16x8*)(vn + CC);
    }

    const half_t* Kc = &Kf[cur * 4096];
#pragma unroll
    for (int mi = 0; mi < 2; ++mi) {
      // S^T = K.Q^T per 16-key block; exp+pack immediately (4-VGPR st live range)
#pragma unroll
      for (int kb = 0; kb < 4; ++kb) {
        const f16x8 ka0 = *(const f16x8*)&Kc[((kb * 2 + 0) * 64 + lane) * 8];
        const f16x8 ka1 = *(const f16x8*)&Kc[((kb * 2 + 1) * 64 + lane) * 8];
        f32x4 st = MFMA16(ka0, qa[mi][0], zero);
        st = MFMA16(ka1, qa[mi][1], st);
        f16x4 w;
#pragma unroll
        for (int r = 0; r < 4; ++r) {
          const float p = __builtin_amdgcn_exp2f(st[r] * 0.18033688011112042f);
          lp[mi] += p;
          w[r] = (half_t)p;
        }
        *(f16x4*)&Pb[wave][l16][(kb * 8 + quad * 2) ^ ((l16 & 7) << 2)] = w;
      }

      // O^T += V^T . P^T
#pragma unroll
      for (int kc = 0; kc < 2; ++kc) {
        const f16x8 pa = *(const f16x8*)&Pb[wave][l16][(kc * 16 + quad * 4) ^ ((l16 & 7) << 2)];
#pragma unroll
        for (int nd = 0; nd < 4; ++nd) {
          const f16x8 vb = *(const f16x8*)&Vfd[(((kc * 4 + nd) * 64) + (lx ^ (kc << 2))) * 4];
          o[mi][nd] = MFMA16(vb, pa, o[mi][nd]);
        }
      }
    }
    __syncthreads();  // all waves done reading Kf[cur] and Vfd
    cur ^= 1;
  }

  // epilogue: row sum over quads, normalize, contiguous 8B stores
#pragma unroll
  for (int mi = 0; mi < 2; ++mi) {
    float rs = lp[mi];
    rs += __shfl_xor(rs, 16);
    rs += __shfl_xor(rs, 32);
    const float inv = 1.f / rs;
    const size_t row =
        (size_t)(b * NQ + qblk * 128 + wave * 32 + mi * 16 + l16) * CC + h * HDIM;
#pragma unroll
    for (int nd = 0; nd < 4; ++nd) {
      f16x4 w;
#pragma unroll
      for (int r = 0; r < 4; ++r) w[r] = (half_t)(o[mi][nd][r] * inv);
      *(f16x4*)&x16[row + nd * 16 + quad * 4] = w;
    }
  }
}

// ---------------------------------------------------------------------------
extern "C" void kernel_launch(void* const* d_in, const int* in_sizes, int n_in,
                              void* d_out, int out_size, void* d_ws, size_t ws_size,
                              hipStream_t stream) {
  const float* query = (const float*)d_in[0];
  const float* key   = (const float*)d_in[1];
  const float* value = (const float*)d_in[2];
  const int*   qpos  = (const int*)d_in[3];
  const int*   kpos  = (const int*)d_in[4];
  const float* Wq = (const float*)d_in[5];
  const float* Wk = (const float*)d_in[6];
  const float* Wv = (const float*)d_in[7];
  const float* Wo = (const float*)d_in[8];
  const float* bo = (const float*)d_in[9];
  float* out = (float*)d_out;

  const size_t NT = (size_t)Bc * NQ * CC;  // 8.4M halfs per activation tensor
  half_t* q16 = (half_t*)d_ws;
  half_t* k16 = q16 + NT;
  half_t* v16 = k16 + NT;
  half_t* A0  = v16 + NT;        // fp16 staging for GEMM X input; later x16
  half_t* W16 = A0 + NT;         // 4 weights, fp16, 1M each
  half_t* x16 = A0;

  const int nbA = (int)(NT / 8 / 256);      // 4096 blocks for activation cvt
  const int nbW = (CC * CC) / 8 / 256;      // 512 blocks per weight

  // weights -> fp16 (one batched launch)
  cvtW<<<dim3(nbW, 4), 256, 0, stream>>>(Wq, Wk, Wv, Wo, W16);

  const dim3 gg(CC / 128, Bc * NQ / 128);  // (8, 64)
  // Q/K/V projections (A0 reused serially; stream order serializes)
  cvt16<<<nbA, 256, 0, stream>>>(query, A0);
  gemm_lds<false><<<gg, 256, 0, stream>>>(A0, W16 + 0 * (size_t)CC * CC, q16, nullptr, nullptr);
  cvt16<<<nbA, 256, 0, stream>>>(key, A0);
  gemm_lds<false><<<gg, 256, 0, stream>>>(A0, W16 + 1 * (size_t)CC * CC, k16, nullptr, nullptr);
  cvt16<<<nbA, 256, 0, stream>>>(value, A0);
  gemm_lds<false><<<gg, 256, 0, stream>>>(A0, W16 + 2 * (size_t)CC * CC, v16, nullptr, nullptr);

  rope_kernel<<<(Bc * NQ * NHD * 32) / 256, 256, 0, stream>>>(q16, qpos);
  rope_kernel<<<(Bc * NQ * NHD * 32) / 256, 256, 0, stream>>>(k16, kpos);

  attn_kernel<<<dim3(NQ / 128, NHD, Bc), 256, 0, stream>>>(q16, k16, v16, x16);

  gemm_lds<true><<<gg, 256, 0, stream>>>(x16, W16 + 3 * (size_t)CC * CC, nullptr, out, bo);
}

// Round 4
// 428.882 us; speedup vs baseline: 1.5010x; 1.0806x over previous
//
#include <hip/hip_runtime.h>
#include <math.h>

typedef _Float16 half_t;
typedef __attribute__((ext_vector_type(8))) _Float16 f16x8;
typedef __attribute__((ext_vector_type(4))) _Float16 f16x4;
typedef __attribute__((ext_vector_type(4))) float f32x4;

#define MFMA16(a, b, c) __builtin_amdgcn_mfma_f32_16x16x32_f16((a), (b), (c), 0, 0, 0)

constexpr int Bc = 4, NQ = 2048, NKC = 2048, CC = 1024, NHD = 16, HDIM = 64;

__device__ __forceinline__ void async_copy16(half_t* lds, const half_t* g) {
  __builtin_amdgcn_global_load_lds(
      (const __attribute__((address_space(1))) unsigned*)g,
      (__attribute__((address_space(3))) unsigned*)lds, 16, 0, 0);
}

// ---------------------------------------------------------------------------
// fp32 -> fp16 converts (8 elems/thread)
// ---------------------------------------------------------------------------
__global__ __launch_bounds__(256) void cvt16(const float* __restrict__ src,
                                             half_t* __restrict__ dst) {
  const int i = blockIdx.x * 256 + threadIdx.x;
  const f32x4 a = ((const f32x4*)src)[2 * i];
  const f32x4 b = ((const f32x4*)src)[2 * i + 1];
  f16x8 h;
#pragma unroll
  for (int j = 0; j < 4; ++j) { h[j] = (half_t)a[j]; h[4 + j] = (half_t)b[j]; }
  ((f16x8*)dst)[i] = h;
}

__global__ __launch_bounds__(256) void cvtW(const float* __restrict__ s0,
                                            const float* __restrict__ s1,
                                            const float* __restrict__ s2,
                                            const float* __restrict__ s3,
                                            half_t* __restrict__ dst) {
  const int y = blockIdx.y;
  const float* src = (y == 0) ? s0 : (y == 1) ? s1 : (y == 2) ? s2 : s3;
  const int i = blockIdx.x * 256 + threadIdx.x;
  const f32x4 a = ((const f32x4*)src)[2 * i];
  const f32x4 b = ((const f32x4*)src)[2 * i + 1];
  f16x8 h;
#pragma unroll
  for (int j = 0; j < 4; ++j) { h[j] = (half_t)a[j]; h[4 + j] = (half_t)b[j]; }
  ((f16x8*)(dst + (size_t)y * CC * CC))[i] = h;
}

// ---------------------------------------------------------------------------
// GEMM (m97 structure): out[m][n] = sum_k X[m][k]*W[n][k], fp16 in, MFMA.
// 128x128 tile, BK=32, unpadded LDS, global_load_lds width 16.
// ---------------------------------------------------------------------------
template <bool FINAL>
__global__ __launch_bounds__(256) void gemm_lds(const half_t* __restrict__ X,
                                                const half_t* __restrict__ W,
                                                half_t* __restrict__ out16,
                                                float* __restrict__ outf,
                                                const float* __restrict__ bias) {
  __shared__ half_t As[128 * 32];
  __shared__ half_t Bs[128 * 32];
  const int tid  = threadIdx.x;
  const int wave = tid >> 6, lane = tid & 63;
  const int quad = lane >> 4, l16 = lane & 15;
  const int m0 = blockIdx.y * 128, n0 = blockIdx.x * 128;
  const int mw = (wave >> 1) * 64, nw = (wave & 1) * 64;

  // staging: instr i in {0,1} covers rows wave*32+i*16 .. +16, lane: row+=l/4, k=(l&3)*8
  const int srow = lane >> 2, skoff = (lane & 3) * 8;
  const half_t* xa = X + (size_t)(m0 + wave * 32 + srow) * CC + skoff;
  const half_t* xb = W + (size_t)(n0 + wave * 32 + srow) * CC + skoff;
  half_t* lA0 = &As[(wave * 2 + 0) * 512];
  half_t* lA1 = &As[(wave * 2 + 1) * 512];
  half_t* lB0 = &Bs[(wave * 2 + 0) * 512];
  half_t* lB1 = &Bs[(wave * 2 + 1) * 512];

  f32x4 acc[4][4] = {};

  for (int k0 = 0; k0 < CC; k0 += 32) {
    __syncthreads();
    async_copy16(lA0, xa + k0);
    async_copy16(lA1, xa + 16 * CC + k0);
    async_copy16(lB0, xb + k0);
    async_copy16(lB1, xb + 16 * CC + k0);
    __syncthreads();

    f16x8 af[4], bf[4];
#pragma unroll
    for (int mi = 0; mi < 4; ++mi) af[mi] = *(const f16x8*)&As[(mw + mi * 16 + l16) * 32 + quad * 8];
#pragma unroll
    for (int ni = 0; ni < 4; ++ni) bf[ni] = *(const f16x8*)&Bs[(nw + ni * 16 + l16) * 32 + quad * 8];
#pragma unroll
    for (int mi = 0; mi < 4; ++mi)
#pragma unroll
      for (int ni = 0; ni < 4; ++ni) acc[mi][ni] = MFMA16(af[mi], bf[ni], acc[mi][ni]);
  }

#pragma unroll
  for (int mi = 0; mi < 4; ++mi)
#pragma unroll
    for (int ni = 0; ni < 4; ++ni)
#pragma unroll
      for (int r = 0; r < 4; ++r) {
        const size_t row = (size_t)(m0 + mw + mi * 16 + quad * 4 + r);
        const size_t col = (size_t)(n0 + nw + ni * 16 + l16);
        if constexpr (FINAL) outf[row * CC + col] = acc[mi][ni][r] + bias[col];
        else                 out16[row * CC + col] = (half_t)acc[mi][ni][r];
      }
}

// ---------------------------------------------------------------------------
// RoPE2D in fp16, in place (exact numpy-fp16 elementwise emulation).
// ---------------------------------------------------------------------------
__global__ __launch_bounds__(256) void rope_kernel(half_t* __restrict__ t,
                                                   const int* __restrict__ pos) {
#pragma clang fp contract(off)
  const int gid = blockIdx.x * 256 + threadIdx.x;
  const int i       = gid & 15;
  const int halfsel = (gid >> 4) & 1;
  const int h       = (gid >> 5) & 15;
  const int n       = (gid >> 9) & 2047;
  const int b       = gid >> 20;

  const int p = pos[((b * NQ + n) << 1) + halfsel];
  const float inv = __builtin_amdgcn_exp2f((float)i * -0.41524100904865773f);
  const float ang = (float)p * inv;
  const half_t hc = (half_t)cosf(ang);
  const half_t hs = (half_t)sinf(ang);

  const size_t base = (size_t)(b * NQ + n) * CC + h * HDIM + halfsel * 32;
  const half_t t1 = t[base + i];
  const half_t t2 = t[base + 16 + i];
  const half_t p1 = t1 * hc;
  const half_t p2 = t2 * hs;
  const half_t p3 = t2 * hc;
  const half_t p4 = t1 * hs;
  t[base + i]      = p1 - p2;
  t[base + 16 + i] = p3 + p4;
}

// ---------------------------------------------------------------------------
// Flash attention, swapped-operand, batched-phase pipeline.
//   K: double-buffered global_load_lds, fragment-ordered via per-lane source.
//   V: reg-staged transpose pack, single swizzled buffer.
//   Per tile: pack V -> full __syncthreads (drains K gll, issued a full tile
//   ago) -> issue next K gll + V reg loads -> ALL QK MFMA + exp + in-lane
//   pack (both mi) -> one Pb settle -> ALL PV MFMA (V frags shared across
//   mi) -> rendezvous-only "s_waitcnt lgkmcnt(0)" + s_barrier builtin
//   (next-tile loads stay in flight across it).
// LDS = 16 (Kf dbuf) + 8 (Vfd) + 16 (Pb) = 40 KB -> 4 blocks/CU (= grid cap).
// ---------------------------------------------------------------------------
__global__ __launch_bounds__(256, 3) void attn_kernel(const half_t* __restrict__ q16,
                                                      const half_t* __restrict__ k16,
                                                      const half_t* __restrict__ v16,
                                                      half_t* __restrict__ x16) {
  // K fragments, double-buffered: [buf][kb][kc][slot=quad*16+l16][8 halfs] (16 KB)
  __shared__ __align__(16) half_t Kf[2 * 4096];
  // V^T fragments: [kc][nd][slot'][8 halfs], slot' = quad*16 + (l16 ^ quad ^ (kc<<2)) (8 KB)
  __shared__ __align__(16) unsigned Vfd[2 * 4 * 64 * 4];
  // P key-pair dwords: [wave][mi][q=l16][m ^ ((l16&7)<<2)], m = key/2 (16 KB)
  __shared__ __align__(16) unsigned Pb[4][2][16][32];

  const int tid  = threadIdx.x;
  const int wave = tid >> 6, lane = tid & 63;
  const int quad = lane >> 4, l16 = lane & 15;
  const int lx   = lane ^ quad;  // V-read slot base (quad XORed into low bits)
  const int psw  = (l16 & 7) << 2;
  const int qblk = blockIdx.x, h = blockIdx.y, b = blockIdx.z;
  const f32x4 zero = {0.f, 0.f, 0.f, 0.f};

  // Q fragments (B-operand role): rows wave*32 + mi*16 + l16, k = kc*32 + quad*8
  f16x8 qa[2][2];
  {
    const half_t* qbase =
        q16 + (size_t)(b * NQ + qblk * 128 + wave * 32 + l16) * CC + h * HDIM + quad * 8;
#pragma unroll
    for (int mi = 0; mi < 2; ++mi)
#pragma unroll
      for (int kc = 0; kc < 2; ++kc)
        qa[mi][kc] = *(const f16x8*)(qbase + (size_t)mi * 16 * CC + kc * 32);
  }

  f32x4 o[2][4] = {};   // O^T fragments: [mi][nd], rows d = nd*16+quad*4+r, col q = l16
  f32x4 lpv[2] = {};    // per-lane partial row sums, split by r (short add chains)

  // K gll: wave w stages kb=w. Per-lane global source so linear LDS dest
  // (base + lane*16) lands in fragment order: key = w*16 + l16, d = quad*8 + kc*32.
  const half_t* kga = k16 + (size_t)(b * NKC + wave * 16 + l16) * CC + h * HDIM + quad * 8;

  // V staging: thread covers keys {2vp, 2vp+1}, d = vd0..vd0+7
  const int vp = tid & 31, vd0 = (tid >> 5) * 8;
  const half_t* vptr = v16 + (size_t)(b * NKC + 2 * vp) * CC + h * HDIM + vd0;
  const int vkc = vp >> 4, vqd = (vp & 15) >> 2, vnd = vd0 >> 4;
  const int vl16b = vd0 & 15;  // 0 or 8
  const int vswz  = vqd ^ (vkc << 2);
  const int vbase = ((vkc * 4 + vnd) * 64 + vqd * 16) * 4 + (vp & 3);

  // prologue: tile 0 in flight
  async_copy16(&Kf[(wave * 2 + 0) * 512], kga);
  async_copy16(&Kf[(wave * 2 + 1) * 512], kga + 32);
  f16x8 vr0 = *(const f16x8*)vptr;
  f16x8 vr1 = *(const f16x8*)(vptr + CC);

  int cur = 0;
  for (int kt = 0; kt < NKC; kt += 64) {
    // V transpose-pack into Vfd (this tile); rendezvous barrier of prev iter
    // guarantees all waves' reads of Vfd are complete.
#pragma unroll
    for (int i = 0; i < 8; ++i) {
      union { half_t h2[2]; unsigned u; } pk;
      pk.h2[0] = vr0[i]; pk.h2[1] = vr1[i];
      Vfd[vbase + (((vl16b + i) ^ vswz) << 2)] = pk.u;
    }
    __syncthreads();  // full drain: Kf[cur] gll (issued a tile ago) landed; Vfd visible

    if (kt + 64 < NKC) {  // issue next K tile (other buffer) + next V reg loads
      const half_t* kn = kga + (size_t)(kt + 64) * CC;
      async_copy16(&Kf[(cur ^ 1) * 4096 + (wave * 2 + 0) * 512], kn);
      async_copy16(&Kf[(cur ^ 1) * 4096 + (wave * 2 + 1) * 512], kn + 32);
      const half_t* vn = vptr + (size_t)(kt + 64) * CC;
      vr0 = *(const f16x8*)vn;
      vr1 = *(const f16x8*)(vn + CC);
    }

    const half_t* Kc = &Kf[cur * 4096];

    // Phase 1: S^T = K.Q^T for BOTH mi; exp + in-lane pack per kb (short live ranges)
#pragma unroll
    for (int mi = 0; mi < 2; ++mi)
#pragma unroll
      for (int kb = 0; kb < 4; ++kb) {
        const f16x8 ka0 = *(const f16x8*)&Kc[((kb * 2 + 0) * 64 + lane) * 8];
        const f16x8 ka1 = *(const f16x8*)&Kc[((kb * 2 + 1) * 64 + lane) * 8];
        f32x4 st = MFMA16(ka0, qa[mi][0], zero);
        st = MFMA16(ka1, qa[mi][1], st);
        f16x4 w;
#pragma unroll
        for (int r = 0; r < 4; ++r) {
          const float p = __builtin_amdgcn_exp2f(st[r] * 0.18033688011112042f);
          lpv[mi][r] += p;
          w[r] = (half_t)p;
        }
        *(f16x4*)&Pb[wave][mi][l16][(kb * 8 + quad * 2) ^ psw] = w;
      }

    // Phase 2: O^T += V^T . P^T  (V fragment read once, shared across mi)
#pragma unroll
    for (int kc = 0; kc < 2; ++kc) {
      const f16x8 pa0 = *(const f16x8*)&Pb[wave][0][l16][(kc * 16 + quad * 4) ^ psw];
      const f16x8 pa1 = *(const f16x8*)&Pb[wave][1][l16][(kc * 16 + quad * 4) ^ psw];
#pragma unroll
      for (int nd = 0; nd < 4; ++nd) {
        const f16x8 vb = *(const f16x8*)&Vfd[(((kc * 4 + nd) * 64) + (lx ^ (kc << 2))) * 4];
        o[0][nd] = MFMA16(vb, pa0, o[0][nd]);
        o[1][nd] = MFMA16(vb, pa1, o[1][nd]);
      }
    }

    // Rendezvous-only barrier: local LDS ops drained, but next-tile K gll and
    // V register loads stay in flight across it (no vmcnt drain).
    asm volatile("s_waitcnt lgkmcnt(0)" ::: "memory");
    __builtin_amdgcn_s_barrier();
    cur ^= 1;
  }

  // epilogue: row sum over quads, normalize, contiguous 8B stores
#pragma unroll
  for (int mi = 0; mi < 2; ++mi) {
    float rs = (lpv[mi][0] + lpv[mi][1]) + (lpv[mi][2] + lpv[mi][3]);
    rs += __shfl_xor(rs, 16);
    rs += __shfl_xor(rs, 32);
    const float inv = 1.f / rs;
    const size_t row =
        (size_t)(b * NQ + qblk * 128 + wave * 32 + mi * 16 + l16) * CC + h * HDIM;
#pragma unroll
    for (int nd = 0; nd < 4; ++nd) {
      f16x4 w;
#pragma unroll
      for (int r = 0; r < 4; ++r) w[r] = (half_t)(o[mi][nd][r] * inv);
      *(f16x4*)&x16[row + nd * 16 + quad * 4] = w;
    }
  }
}

// ---------------------------------------------------------------------------
extern "C" void kernel_launch(void* const* d_in, const int* in_sizes, int n_in,
                              void* d_out, int out_size, void* d_ws, size_t ws_size,
                              hipStream_t stream) {
  const float* query = (const float*)d_in[0];
  const float* key   = (const float*)d_in[1];
  const float* value = (const float*)d_in[2];
  const int*   qpos  = (const int*)d_in[3];
  const int*   kpos  = (const int*)d_in[4];
  const float* Wq = (const float*)d_in[5];
  const float* Wk = (const float*)d_in[6];
  const float* Wv = (const float*)d_in[7];
  const float* Wo = (const float*)d_in[8];
  const float* bo = (const float*)d_in[9];
  float* out = (float*)d_out;

  const size_t NT = (size_t)Bc * NQ * CC;  // 8.4M halfs per activation tensor
  half_t* q16 = (half_t*)d_ws;
  half_t* k16 = q16 + NT;
  half_t* v16 = k16 + NT;
  half_t* A0  = v16 + NT;        // fp16 staging for GEMM X input; later x16
  half_t* W16 = A0 + NT;         // 4 weights, fp16, 1M each
  half_t* x16 = A0;

  const int nbA = (int)(NT / 8 / 256);      // 4096 blocks for activation cvt
  const int nbW = (CC * CC) / 8 / 256;      // 512 blocks per weight

  // weights -> fp16 (one batched launch)
  cvtW<<<dim3(nbW, 4), 256, 0, stream>>>(Wq, Wk, Wv, Wo, W16);

  const dim3 gg(CC / 128, Bc * NQ / 128);  // (8, 64)
  // Q/K/V projections (A0 reused serially; stream order serializes)
  cvt16<<<nbA, 256, 0, stream>>>(query, A0);
  gemm_lds<false><<<gg, 256, 0, stream>>>(A0, W16 + 0 * (size_t)CC * CC, q16, nullptr, nullptr);
  cvt16<<<nbA, 256, 0, stream>>>(key, A0);
  gemm_lds<false><<<gg, 256, 0, stream>>>(A0, W16 + 1 * (size_t)CC * CC, k16, nullptr, nullptr);
  cvt16<<<nbA, 256, 0, stream>>>(value, A0);
  gemm_lds<false><<<gg, 256, 0, stream>>>(A0, W16 + 2 * (size_t)CC * CC, v16, nullptr, nullptr);

  rope_kernel<<<(Bc * NQ * NHD * 32) / 256, 256, 0, stream>>>(q16, qpos);
  rope_kernel<<<(Bc * NQ * NHD * 32) / 256, 256, 0, stream>>>(k16, kpos);

  attn_kernel<<<dim3(NQ / 128, NHD, Bc), 256, 0, stream>>>(q16, k16, v16, x16);

  gemm_lds<true><<<gg, 256, 0, stream>>>(x16, W16 + 3 * (size_t)CC * CC, nullptr, out, bo);
}

// Round 5
// 404.984 us; speedup vs baseline: 1.5896x; 1.0590x over previous
//
#include <hip/hip_runtime.h>
#include <math.h>

typedef _Float16 half_t;
typedef __attribute__((ext_vector_type(8))) _Float16 f16x8;
typedef __attribute__((ext_vector_type(4))) _Float16 f16x4;
typedef __attribute__((ext_vector_type(4))) float f32x4;

#define MFMA16(a, b, c) __builtin_amdgcn_mfma_f32_16x16x32_f16((a), (b), (c), 0, 0, 0)

constexpr int Bc = 4, NQ = 2048, NKC = 2048, CC = 1024, NHD = 16, HDIM = 64;

__device__ __forceinline__ void async_copy16(half_t* lds, const half_t* g) {
  __builtin_amdgcn_global_load_lds(
      (const __attribute__((address_space(1))) unsigned*)g,
      (__attribute__((address_space(3))) unsigned*)lds, 16, 0, 0);
}

// ---------------------------------------------------------------------------
// fp32 -> fp16 converts (8 elems/thread)
// ---------------------------------------------------------------------------
__global__ __launch_bounds__(256) void cvt16(const float* __restrict__ src,
                                             half_t* __restrict__ dst) {
  const int i = blockIdx.x * 256 + threadIdx.x;
  const f32x4 a = ((const f32x4*)src)[2 * i];
  const f32x4 b = ((const f32x4*)src)[2 * i + 1];
  f16x8 h;
#pragma unroll
  for (int j = 0; j < 4; ++j) { h[j] = (half_t)a[j]; h[4 + j] = (half_t)b[j]; }
  ((f16x8*)dst)[i] = h;
}

__global__ __launch_bounds__(256) void cvtW(const float* __restrict__ s0,
                                            const float* __restrict__ s1,
                                            const float* __restrict__ s2,
                                            const float* __restrict__ s3,
                                            half_t* __restrict__ dst) {
  const int y = blockIdx.y;
  const float* src = (y == 0) ? s0 : (y == 1) ? s1 : (y == 2) ? s2 : s3;
  const int i = blockIdx.x * 256 + threadIdx.x;
  const f32x4 a = ((const f32x4*)src)[2 * i];
  const f32x4 b = ((const f32x4*)src)[2 * i + 1];
  f16x8 h;
#pragma unroll
  for (int j = 0; j < 4; ++j) { h[j] = (half_t)a[j]; h[4 + j] = (half_t)b[j]; }
  ((f16x8*)(dst + (size_t)y * CC * CC))[i] = h;
}

// ---------------------------------------------------------------------------
// GEMM (m97 structure): out[m][n] = sum_k X[m][k]*W[n][k], fp16 in, MFMA.
// 128x128 tile, BK=32, unpadded LDS, global_load_lds width 16.
// ---------------------------------------------------------------------------
template <bool FINAL>
__global__ __launch_bounds__(256) void gemm_lds(const half_t* __restrict__ X,
                                                const half_t* __restrict__ W,
                                                half_t* __restrict__ out16,
                                                float* __restrict__ outf,
                                                const float* __restrict__ bias) {
  __shared__ half_t As[128 * 32];
  __shared__ half_t Bs[128 * 32];
  const int tid  = threadIdx.x;
  const int wave = tid >> 6, lane = tid & 63;
  const int quad = lane >> 4, l16 = lane & 15;
  const int m0 = blockIdx.y * 128, n0 = blockIdx.x * 128;
  const int mw = (wave >> 1) * 64, nw = (wave & 1) * 64;

  // staging: instr i in {0,1} covers rows wave*32+i*16 .. +16, lane: row+=l/4, k=(l&3)*8
  const int srow = lane >> 2, skoff = (lane & 3) * 8;
  const half_t* xa = X + (size_t)(m0 + wave * 32 + srow) * CC + skoff;
  const half_t* xb = W + (size_t)(n0 + wave * 32 + srow) * CC + skoff;
  half_t* lA0 = &As[(wave * 2 + 0) * 512];
  half_t* lA1 = &As[(wave * 2 + 1) * 512];
  half_t* lB0 = &Bs[(wave * 2 + 0) * 512];
  half_t* lB1 = &Bs[(wave * 2 + 1) * 512];

  f32x4 acc[4][4] = {};

  for (int k0 = 0; k0 < CC; k0 += 32) {
    __syncthreads();
    async_copy16(lA0, xa + k0);
    async_copy16(lA1, xa + 16 * CC + k0);
    async_copy16(lB0, xb + k0);
    async_copy16(lB1, xb + 16 * CC + k0);
    __syncthreads();

    f16x8 af[4], bf[4];
#pragma unroll
    for (int mi = 0; mi < 4; ++mi) af[mi] = *(const f16x8*)&As[(mw + mi * 16 + l16) * 32 + quad * 8];
#pragma unroll
    for (int ni = 0; ni < 4; ++ni) bf[ni] = *(const f16x8*)&Bs[(nw + ni * 16 + l16) * 32 + quad * 8];
#pragma unroll
    for (int mi = 0; mi < 4; ++mi)
#pragma unroll
      for (int ni = 0; ni < 4; ++ni) acc[mi][ni] = MFMA16(af[mi], bf[ni], acc[mi][ni]);
  }

#pragma unroll
  for (int mi = 0; mi < 4; ++mi)
#pragma unroll
    for (int ni = 0; ni < 4; ++ni)
#pragma unroll
      for (int r = 0; r < 4; ++r) {
        const size_t row = (size_t)(m0 + mw + mi * 16 + quad * 4 + r);
        const size_t col = (size_t)(n0 + nw + ni * 16 + l16);
        if constexpr (FINAL) outf[row * CC + col] = acc[mi][ni][r] + bias[col];
        else                 out16[row * CC + col] = (half_t)acc[mi][ni][r];
      }
}

// ---------------------------------------------------------------------------
// RoPE2D in fp16, in place (exact numpy-fp16 elementwise emulation).
// ---------------------------------------------------------------------------
__global__ __launch_bounds__(256) void rope_kernel(half_t* __restrict__ t,
                                                   const int* __restrict__ pos) {
#pragma clang fp contract(off)
  const int gid = blockIdx.x * 256 + threadIdx.x;
  const int i       = gid & 15;
  const int halfsel = (gid >> 4) & 1;
  const int h       = (gid >> 5) & 15;
  const int n       = (gid >> 9) & 2047;
  const int b       = gid >> 20;

  const int p = pos[((b * NQ + n) << 1) + halfsel];
  const float inv = __builtin_amdgcn_exp2f((float)i * -0.41524100904865773f);
  const float ang = (float)p * inv;
  const half_t hc = (half_t)cosf(ang);
  const half_t hs = (half_t)sinf(ang);

  const size_t base = (size_t)(b * NQ + n) * CC + h * HDIM + halfsel * 32;
  const half_t t1 = t[base + i];
  const half_t t2 = t[base + 16 + i];
  const half_t p1 = t1 * hc;
  const half_t p2 = t2 * hs;
  const half_t p3 = t2 * hc;
  const half_t p4 = t1 * hs;
  t[base + i]      = p1 - p2;
  t[base + 16 + i] = p3 + p4;
}

// ---------------------------------------------------------------------------
// Flash attention, swapped-operand, batched-phase pipeline.
//   K: double-buffered global_load_lds, fragment-ordered via per-lane source.
//   V: reg-staged transpose pack, single swizzled buffer.
//   QK phase: K-frag pair read once per kb (shared across mi), ALL 16 MFMAs
//   issued into live st[2][4] (max ILP), THEN batched exp+pack pass and
//   8 ds_write_b64 -> one Pb settle -> ALL PV MFMA (V frags shared across
//   mi) -> rendezvous-only "s_waitcnt lgkmcnt(0)" + s_barrier (next-tile
//   loads stay in flight across it).
// LDS = 16 (Kf dbuf) + 8 (Vfd) + 16 (Pb) = 40 KB -> 4 blocks/CU.
// launch_bounds(256,4): pin VGPR <= 128 so 4 waves/SIMD are VGPR-feasible
// (est. pressure ~115; WRITE_SIZE is the spill tripwire).
// ---------------------------------------------------------------------------
__global__ __launch_bounds__(256, 4) void attn_kernel(const half_t* __restrict__ q16,
                                                      const half_t* __restrict__ k16,
                                                      const half_t* __restrict__ v16,
                                                      half_t* __restrict__ x16) {
  // K fragments, double-buffered: [buf][kb][kc][slot=quad*16+l16][8 halfs] (16 KB)
  __shared__ __align__(16) half_t Kf[2 * 4096];
  // V^T fragments: [kc][nd][slot'][8 halfs], slot' = quad*16 + (l16 ^ quad ^ (kc<<2)) (8 KB)
  __shared__ __align__(16) unsigned Vfd[2 * 4 * 64 * 4];
  // P key-pair dwords: [wave][mi][q=l16][m ^ ((l16&7)<<2)], m = key/2 (16 KB)
  __shared__ __align__(16) unsigned Pb[4][2][16][32];

  const int tid  = threadIdx.x;
  const int wave = tid >> 6, lane = tid & 63;
  const int quad = lane >> 4, l16 = lane & 15;
  const int lx   = lane ^ quad;  // V-read slot base (quad XORed into low bits)
  const int psw  = (l16 & 7) << 2;
  const int qblk = blockIdx.x, h = blockIdx.y, b = blockIdx.z;
  const f32x4 zero = {0.f, 0.f, 0.f, 0.f};

  // Q fragments (B-operand role): rows wave*32 + mi*16 + l16, k = kc*32 + quad*8
  f16x8 qa[2][2];
  {
    const half_t* qbase =
        q16 + (size_t)(b * NQ + qblk * 128 + wave * 32 + l16) * CC + h * HDIM + quad * 8;
#pragma unroll
    for (int mi = 0; mi < 2; ++mi)
#pragma unroll
      for (int kc = 0; kc < 2; ++kc)
        qa[mi][kc] = *(const f16x8*)(qbase + (size_t)mi * 16 * CC + kc * 32);
  }

  f32x4 o[2][4] = {};   // O^T fragments: [mi][nd], rows d = nd*16+quad*4+r, col q = l16
  f32x4 lpv[2] = {};    // per-lane partial row sums, split by r (short add chains)

  // K gll: wave w stages kb=w. Per-lane global source so linear LDS dest
  // (base + lane*16) lands in fragment order: key = w*16 + l16, d = quad*8 + kc*32.
  const half_t* kga = k16 + (size_t)(b * NKC + wave * 16 + l16) * CC + h * HDIM + quad * 8;

  // V staging: thread covers keys {2vp, 2vp+1}, d = vd0..vd0+7
  const int vp = tid & 31, vd0 = (tid >> 5) * 8;
  const half_t* vptr = v16 + (size_t)(b * NKC + 2 * vp) * CC + h * HDIM + vd0;
  const int vkc = vp >> 4, vqd = (vp & 15) >> 2, vnd = vd0 >> 4;
  const int vl16b = vd0 & 15;  // 0 or 8
  const int vswz  = vqd ^ (vkc << 2);
  const int vbase = ((vkc * 4 + vnd) * 64 + vqd * 16) * 4 + (vp & 3);

  // prologue: tile 0 in flight
  async_copy16(&Kf[(wave * 2 + 0) * 512], kga);
  async_copy16(&Kf[(wave * 2 + 1) * 512], kga + 32);
  f16x8 vr0 = *(const f16x8*)vptr;
  f16x8 vr1 = *(const f16x8*)(vptr + CC);

  int cur = 0;
  for (int kt = 0; kt < NKC; kt += 64) {
    // V transpose-pack into Vfd (this tile); rendezvous barrier of prev iter
    // guarantees all waves' reads of Vfd are complete.
#pragma unroll
    for (int i = 0; i < 8; ++i) {
      union { half_t h2[2]; unsigned u; } pk;
      pk.h2[0] = vr0[i]; pk.h2[1] = vr1[i];
      Vfd[vbase + (((vl16b + i) ^ vswz) << 2)] = pk.u;
    }
    __syncthreads();  // full drain: Kf[cur] gll (issued a tile ago) landed; Vfd visible

    if (kt + 64 < NKC) {  // issue next K tile (other buffer) + next V reg loads
      const half_t* kn = kga + (size_t)(kt + 64) * CC;
      async_copy16(&Kf[(cur ^ 1) * 4096 + (wave * 2 + 0) * 512], kn);
      async_copy16(&Kf[(cur ^ 1) * 4096 + (wave * 2 + 1) * 512], kn + 32);
      const half_t* vn = vptr + (size_t)(kt + 64) * CC;
      vr0 = *(const f16x8*)vn;
      vr1 = *(const f16x8*)(vn + CC);
    }

    const half_t* Kc = &Kf[cur * 4096];

    // Phase 1a: S^T = K.Q^T, ALL 16 MFMAs live in st[2][4] (K-frags read once per kb)
    f32x4 st[2][4];
    __builtin_amdgcn_s_setprio(1);
#pragma unroll
    for (int kb = 0; kb < 4; ++kb) {
      const f16x8 ka0 = *(const f16x8*)&Kc[((kb * 2 + 0) * 64 + lane) * 8];
      const f16x8 ka1 = *(const f16x8*)&Kc[((kb * 2 + 1) * 64 + lane) * 8];
#pragma unroll
      for (int mi = 0; mi < 2; ++mi) {
        const f32x4 t0 = MFMA16(ka0, qa[mi][0], zero);
        st[mi][kb] = MFMA16(ka1, qa[mi][1], t0);
      }
    }
    __builtin_amdgcn_s_setprio(0);

    // Phase 1b: batched exp + in-lane pack + 8 ds_write_b64
#pragma unroll
    for (int mi = 0; mi < 2; ++mi)
#pragma unroll
      for (int kb = 0; kb < 4; ++kb) {
        f16x4 w;
#pragma unroll
        for (int r = 0; r < 4; ++r) {
          const float p = __builtin_amdgcn_exp2f(st[mi][kb][r] * 0.18033688011112042f);
          lpv[mi][r] += p;
          w[r] = (half_t)p;
        }
        *(f16x4*)&Pb[wave][mi][l16][(kb * 8 + quad * 2) ^ psw] = w;
      }

    // Phase 2: O^T += V^T . P^T  (V fragment read once, shared across mi)
    __builtin_amdgcn_s_setprio(1);
#pragma unroll
    for (int kc = 0; kc < 2; ++kc) {
      const f16x8 pa0 = *(const f16x8*)&Pb[wave][0][l16][(kc * 16 + quad * 4) ^ psw];
      const f16x8 pa1 = *(const f16x8*)&Pb[wave][1][l16][(kc * 16 + quad * 4) ^ psw];
#pragma unroll
      for (int nd = 0; nd < 4; ++nd) {
        const f16x8 vb = *(const f16x8*)&Vfd[(((kc * 4 + nd) * 64) + (lx ^ (kc << 2))) * 4];
        o[0][nd] = MFMA16(vb, pa0, o[0][nd]);
        o[1][nd] = MFMA16(vb, pa1, o[1][nd]);
      }
    }
    __builtin_amdgcn_s_setprio(0);

    // Rendezvous-only barrier: local LDS ops drained, but next-tile K gll and
    // V register loads stay in flight across it (no vmcnt drain).
    asm volatile("s_waitcnt lgkmcnt(0)" ::: "memory");
    __builtin_amdgcn_s_barrier();
    cur ^= 1;
  }

  // epilogue: row sum over quads, normalize, contiguous 8B stores
#pragma unroll
  for (int mi = 0; mi < 2; ++mi) {
    float rs = (lpv[mi][0] + lpv[mi][1]) + (lpv[mi][2] + lpv[mi][3]);
    rs += __shfl_xor(rs, 16);
    rs += __shfl_xor(rs, 32);
    const float inv = 1.f / rs;
    const size_t row =
        (size_t)(b * NQ + qblk * 128 + wave * 32 + mi * 16 + l16) * CC + h * HDIM;
#pragma unroll
    for (int nd = 0; nd < 4; ++nd) {
      f16x4 w;
#pragma unroll
      for (int r = 0; r < 4; ++r) w[r] = (half_t)(o[mi][nd][r] * inv);
      *(f16x4*)&x16[row + nd * 16 + quad * 4] = w;
    }
  }
}

// ---------------------------------------------------------------------------
extern "C" void kernel_launch(void* const* d_in, const int* in_sizes, int n_in,
                              void* d_out, int out_size, void* d_ws, size_t ws_size,
                              hipStream_t stream) {
  const float* query = (const float*)d_in[0];
  const float* key   = (const float*)d_in[1];
  const float* value = (const float*)d_in[2];
  const int*   qpos  = (const int*)d_in[3];
  const int*   kpos  = (const int*)d_in[4];
  const float* Wq = (const float*)d_in[5];
  const float* Wk = (const float*)d_in[6];
  const float* Wv = (const float*)d_in[7];
  const float* Wo = (const float*)d_in[8];
  const float* bo = (const float*)d_in[9];
  float* out = (float*)d_out;

  const size_t NT = (size_t)Bc * NQ * CC;  // 8.4M halfs per activation tensor
  half_t* q16 = (half_t*)d_ws;
  half_t* k16 = q16 + NT;
  half_t* v16 = k16 + NT;
  half_t* A0  = v16 + NT;        // fp16 staging for GEMM X input; later x16
  half_t* W16 = A0 + NT;         // 4 weights, fp16, 1M each
  half_t* x16 = A0;

  const int nbA = (int)(NT / 8 / 256);      // 4096 blocks for activation cvt
  const int nbW = (CC * CC) / 8 / 256;      // 512 blocks per weight

  // weights -> fp16 (one batched launch)
  cvtW<<<dim3(nbW, 4), 256, 0, stream>>>(Wq, Wk, Wv, Wo, W16);

  const dim3 gg(CC / 128, Bc * NQ / 128);  // (8, 64)
  // Q/K/V projections (A0 reused serially; stream order serializes)
  cvt16<<<nbA, 256, 0, stream>>>(query, A0);
  gemm_lds<false><<<gg, 256, 0, stream>>>(A0, W16 + 0 * (size_t)CC * CC, q16, nullptr, nullptr);
  cvt16<<<nbA, 256, 0, stream>>>(key, A0);
  gemm_lds<false><<<gg, 256, 0, stream>>>(A0, W16 + 1 * (size_t)CC * CC, k16, nullptr, nullptr);
  cvt16<<<nbA, 256, 0, stream>>>(value, A0);
  gemm_lds<false><<<gg, 256, 0, stream>>>(A0, W16 + 2 * (size_t)CC * CC, v16, nullptr, nullptr);

  rope_kernel<<<(Bc * NQ * NHD * 32) / 256, 256, 0, stream>>>(q16, qpos);
  rope_kernel<<<(Bc * NQ * NHD * 32) / 256, 256, 0, stream>>>(k16, kpos);

  attn_kernel<<<dim3(NQ / 128, NHD, Bc), 256, 0, stream>>>(q16, k16, v16, x16);

  gemm_lds<true><<<gg, 256, 0, stream>>>(x16, W16 + 3 * (size_t)CC * CC, nullptr, out, bo);
}